// Round 2
// baseline (164.734 us; speedup 1.0000x reference)
//
#include <hip/hip_runtime.h>
#include <math.h>

#define E_DIM 8
#define S_DIM 4096
#define B_DIM 8
#define NROWS (B_DIM * S_DIM)          // 32768
#define ROWS_PER_BLOCK 256

// 0.5 (attention scale 1/sqrt(E/NH)=1/2) * log2(e), folded into Q so the
// inner loop uses raw exp2.
#define QSCALE 0.72134752044448170f

__device__ inline float fast_exp2(float x) {
#if __has_builtin(__builtin_amdgcn_exp2f)
    return __builtin_amdgcn_exp2f(x);
#else
    return exp2f(x);
#endif
}

// Kernel 1: Q[row][8] = cos(x@Wq.T+bq+theta)*QSCALE ; KV[row][16] = {k, v}
// interleaved so the attention kernel can fetch one t's k+v with a single
// 64 B scalar load.
__global__ __launch_bounds__(256) void qkv_kernel(
    const float* __restrict__ x,
    const float* __restrict__ Wq, const float* __restrict__ bq,
    const float* __restrict__ Wk, const float* __restrict__ bk,
    const float* __restrict__ Wv, const float* __restrict__ bv,
    const float* __restrict__ theta,
    float* __restrict__ Q, float* __restrict__ KV)
{
    int row = blockIdx.x * blockDim.x + threadIdx.x;   // 0..NROWS-1
    const float4* x4 = (const float4*)(x + (size_t)row * E_DIM);
    float4 xa = x4[0], xb = x4[1];
    float xr[8] = {xa.x, xa.y, xa.z, xa.w, xb.x, xb.y, xb.z, xb.w};

    float q[8], k[8], v[8];
#pragma unroll
    for (int i = 0; i < 8; ++i) {
        float hq = bq[i], hk = bk[i], hv = bv[i];
#pragma unroll
        for (int j = 0; j < 8; ++j) {
            hq += xr[j] * Wq[i * 8 + j];
            hk += xr[j] * Wk[i * 8 + j];
            hv += xr[j] * Wv[i * 8 + j];
        }
        float th = theta[i];
        q[i] = __cosf(hq + th) * QSCALE;   // native v_cos path
        k[i] = __cosf(hk + th);
        v[i] = __cosf(hv + th);
    }

    float4* Q4 = (float4*)(Q + (size_t)row * E_DIM);
    Q4[0] = make_float4(q[0], q[1], q[2], q[3]);
    Q4[1] = make_float4(q[4], q[5], q[6], q[7]);
    float4* KV4 = (float4*)(KV + (size_t)row * 16);
    KV4[0] = make_float4(k[0], k[1], k[2], k[3]);
    KV4[1] = make_float4(k[4], k[5], k[6], k[7]);
    KV4[2] = make_float4(v[0], v[1], v[2], v[3]);
    KV4[3] = make_float4(v[4], v[5], v[6], v[7]);
}

// Kernel 2: flash-style attention partial over one t-chunk. No LDS: k/v
// addresses are wave-uniform -> compiler emits s_load through the scalar
// cache; v_fma takes the SGPR operand directly. No softmax max-subtraction
// needed (|score*log2e| <= 5.8, exp2 bounded by ~54.6).
// grid = (tsplit, NROWS/ROWS_PER_BLOCK); block = 256.
__global__ __launch_bounds__(256) void attn_partial_kernel(
    const float* __restrict__ Q, const float* __restrict__ KV,
    float* __restrict__ ACC, float* __restrict__ DEN, int tchunk)
{
    int tc = blockIdx.x;                 // t-chunk index
    int rb = blockIdx.y;                 // row-block index
    int batch = rb >> 4;                 // 16 row-blocks of 256 per batch row-span of 4096
    int tid = threadIdx.x;
    int row = rb * ROWS_PER_BLOCK + tid;

    const float4* Qg = (const float4*)(Q + (size_t)row * E_DIM);
    float4 q0 = Qg[0], q1 = Qg[1];

    // wave-uniform base for this (batch, chunk)
    const float* kv = KV + ((size_t)batch * S_DIM + (size_t)tc * tchunk) * 16;

    float acc[8] = {0.f, 0.f, 0.f, 0.f, 0.f, 0.f, 0.f, 0.f};
    float den = 0.f;

#pragma unroll 4
    for (int t = 0; t < tchunk; ++t) {
        const float* p = kv + (size_t)t * 16;   // uniform -> s_load_dwordx16
        // two parallel 4-FMA chains to halve dependent latency
        float dA = q0.x * p[0];
        dA = __builtin_fmaf(q0.y, p[1], dA);
        dA = __builtin_fmaf(q0.z, p[2], dA);
        dA = __builtin_fmaf(q0.w, p[3], dA);
        float dB = q1.x * p[4];
        dB = __builtin_fmaf(q1.y, p[5], dB);
        dB = __builtin_fmaf(q1.z, p[6], dB);
        dB = __builtin_fmaf(q1.w, p[7], dB);
        float w = fast_exp2(dA + dB);
        den += w;
#pragma unroll
        for (int j = 0; j < 8; ++j)
            acc[j] = __builtin_fmaf(w, p[8 + j], acc[j]);
    }

    float4* ACC4 = (float4*)(ACC + ((size_t)tc * NROWS + row) * E_DIM);
    ACC4[0] = make_float4(acc[0], acc[1], acc[2], acc[3]);
    ACC4[1] = make_float4(acc[4], acc[5], acc[6], acc[7]);
    DEN[(size_t)tc * NROWS + row] = den;
}

// Kernel 3: reduce partials across t-chunks, normalize, output projection.
__global__ __launch_bounds__(256) void finalize_kernel(
    const float* __restrict__ ACC, const float* __restrict__ DEN,
    const float* __restrict__ Wc, const float* __restrict__ bc,
    float* __restrict__ out, int tsplit)
{
    int row = blockIdx.x * blockDim.x + threadIdx.x;
    float a[8] = {0.f, 0.f, 0.f, 0.f, 0.f, 0.f, 0.f, 0.f};
    float den = 0.f;
    for (int tc = 0; tc < tsplit; ++tc) {
        const float4* A4 = (const float4*)(ACC + ((size_t)tc * NROWS + row) * E_DIM);
        float4 p0 = A4[0], p1 = A4[1];
        a[0] += p0.x; a[1] += p0.y; a[2] += p0.z; a[3] += p0.w;
        a[4] += p1.x; a[5] += p1.y; a[6] += p1.z; a[7] += p1.w;
        den += DEN[(size_t)tc * NROWS + row];
    }
    float inv = 1.0f / den;
#pragma unroll
    for (int j = 0; j < 8; ++j) a[j] *= inv;
    float r[8];
#pragma unroll
    for (int i = 0; i < 8; ++i) {
        float h = bc[i];
#pragma unroll
        for (int j = 0; j < 8; ++j) h += a[j] * Wc[i * 8 + j];
        r[i] = h;
    }
    float4* O4 = (float4*)(out + (size_t)row * E_DIM);
    O4[0] = make_float4(r[0], r[1], r[2], r[3]);
    O4[1] = make_float4(r[4], r[5], r[6], r[7]);
}

extern "C" void kernel_launch(void* const* d_in, const int* in_sizes, int n_in,
                              void* d_out, int out_size, void* d_ws, size_t ws_size,
                              hipStream_t stream) {
    const float* x     = (const float*)d_in[0];
    const float* Wq    = (const float*)d_in[1];
    const float* bq    = (const float*)d_in[2];
    const float* Wk    = (const float*)d_in[3];
    const float* bk    = (const float*)d_in[4];
    const float* Wv    = (const float*)d_in[5];
    const float* bv    = (const float*)d_in[6];
    const float* theta = (const float*)d_in[7];
    const float* Wc    = (const float*)d_in[8];
    const float* bc    = (const float*)d_in[9];
    float* out = (float*)d_out;

    // tsplit=16 -> 2048 blocks -> 8 blocks/CU -> 32 waves/CU (full occupancy),
    // but needs 22 MB of ws. Fall back to 8 (12.6 MB, known to fit) otherwise.
    // ws_size is constant across calls, so this decision is call-invariant.
    int tsplit = 8;
    {
        size_t need16 = ((size_t)NROWS * E_DIM      // Q
                       + (size_t)NROWS * 16          // KV
                       + (size_t)16 * NROWS * E_DIM  // ACC
                       + (size_t)16 * NROWS)         // DEN
                      * sizeof(float);
        if (ws_size >= need16) tsplit = 16;
    }
    int tchunk = S_DIM / tsplit;

    float* ws  = (float*)d_ws;
    float* Q   = ws;
    float* KV  = Q + (size_t)NROWS * E_DIM;
    float* ACC = KV + (size_t)NROWS * 16;
    float* DEN = ACC + (size_t)tsplit * NROWS * E_DIM;

    qkv_kernel<<<NROWS / 256, 256, 0, stream>>>(x, Wq, bq, Wk, bk, Wv, bv, theta, Q, KV);

    dim3 grid2(tsplit, NROWS / ROWS_PER_BLOCK);
    attn_partial_kernel<<<grid2, 256, 0, stream>>>(Q, KV, ACC, DEN, tchunk);

    finalize_kernel<<<NROWS / 256, 256, 0, stream>>>(ACC, DEN, Wc, bc, out, tsplit);
}

// Round 3
// 157.711 us; speedup vs baseline: 1.0445x; 1.0445x over previous
//
#include <hip/hip_runtime.h>
#include <math.h>

#define E_DIM 8
#define S_DIM 4096
#define B_DIM 8
#define NROWS (B_DIM * S_DIM)          // 32768
#define ROWS_PER_BLOCK 512             // 256 threads x 2 rows/lane

// 0.5 (attention scale 1/sqrt(E/NH)=0.5) * log2(e), folded into Q (before f16
// rounding) so the inner loop uses raw exp2.
#define QSCALE 0.72134752044448170f

typedef _Float16 h2 __attribute__((ext_vector_type(2)));

union HU {
    uint4 u;
    h2 h[4];
    _Float16 s[8];
};

__device__ inline float fast_exp2(float x) {
#if __has_builtin(__builtin_amdgcn_exp2f)
    return __builtin_amdgcn_exp2f(x);
#else
    return exp2f(x);
#endif
}

__device__ inline float dot2acc(h2 a, h2 b, float c) {
#if __has_builtin(__builtin_amdgcn_fdot2)
    return __builtin_amdgcn_fdot2(a, b, c, false);
#else
    return __builtin_fmaf((float)a.x, (float)b.x,
           __builtin_fmaf((float)a.y, (float)b.y, c));
#endif
}

// Kernel 1: Qh[row][8] = f16(cos(x@Wq.T+bq+theta)*QSCALE);
// KVh[row][16] = f16{k0..k7, v0..v7} (32 B/t, one LDS-stageable unit).
__global__ __launch_bounds__(256) void qkv_kernel(
    const float* __restrict__ x,
    const float* __restrict__ Wq, const float* __restrict__ bq,
    const float* __restrict__ Wk, const float* __restrict__ bk,
    const float* __restrict__ Wv, const float* __restrict__ bv,
    const float* __restrict__ theta,
    uint2* __restrict__ Qh, uint4* __restrict__ KVh)
{
    int row = blockIdx.x * blockDim.x + threadIdx.x;
    const float4* x4 = (const float4*)(x + (size_t)row * E_DIM);
    float4 xa = x4[0], xb = x4[1];
    float xr[8] = {xa.x, xa.y, xa.z, xa.w, xb.x, xb.y, xb.z, xb.w};

    float q[8], k[8], v[8];
#pragma unroll
    for (int i = 0; i < 8; ++i) {
        float hq = bq[i], hk = bk[i], hv = bv[i];
#pragma unroll
        for (int j = 0; j < 8; ++j) {
            hq += xr[j] * Wq[i * 8 + j];
            hk += xr[j] * Wk[i * 8 + j];
            hv += xr[j] * Wv[i * 8 + j];
        }
        float th = theta[i];
        q[i] = __cosf(hq + th) * QSCALE;
        k[i] = __cosf(hk + th);
        v[i] = __cosf(hv + th);
    }

    union { uint2 u; _Float16 s[4]; } qp[2];
#pragma unroll
    for (int i = 0; i < 8; ++i) qp[i / 4].s[i % 4] = (_Float16)q[i];
    Qh[(size_t)row * 2 + 0] = qp[0].u;
    Qh[(size_t)row * 2 + 1] = qp[1].u;

    HU kv0, kv1;
#pragma unroll
    for (int i = 0; i < 8; ++i) { kv0.s[i] = (_Float16)k[i]; kv1.s[i] = (_Float16)v[i]; }
    KVh[(size_t)row * 2 + 0] = kv0.u;
    KVh[(size_t)row * 2 + 1] = kv1.u;
}

// Kernel 2: flash-style partial over one t-chunk; 2 rows per lane so each
// pair of ds_read_b128 broadcasts feeds 128 (row,t) pairs of work.
// No max-subtraction needed (|score*log2e| <= 5.8).
template <int TSPLIT>
__global__ __launch_bounds__(256) void attn_partial(
    const uint2* __restrict__ Qh, const uint4* __restrict__ KVh,
    float* __restrict__ ACC, float* __restrict__ DEN)
{
    constexpr int TCH = S_DIM / TSPLIT;
    __shared__ uint4 kvs[TCH * 2];     // 32 B per t

    int rb = blockIdx.x;               // row-block: 0..63
    int tc = blockIdx.y;               // t-chunk
    int tid = threadIdx.x;
    int batch = rb >> 3;               // 8 row-blocks of 512 per batch

    // stage chunk: TCH*2 uint4
    const uint4* src = KVh + ((size_t)batch * S_DIM + (size_t)tc * TCH) * 2;
    for (int i = tid; i < TCH * 2; i += 256) kvs[i] = src[i];
    __syncthreads();

    int rowA = rb * ROWS_PER_BLOCK + tid;
    int rowB = rowA + 256;

    union { uint2 u; h2 h[2]; } qa[2], qb[2];
    qa[0].u = Qh[(size_t)rowA * 2 + 0];
    qa[1].u = Qh[(size_t)rowA * 2 + 1];
    qb[0].u = Qh[(size_t)rowB * 2 + 0];
    qb[1].u = Qh[(size_t)rowB * 2 + 1];

    float accA[8] = {0,0,0,0,0,0,0,0}, accB[8] = {0,0,0,0,0,0,0,0};
    float denA = 0.f, denB = 0.f;

#pragma unroll 4
    for (int t = 0; t < TCH; ++t) {
        HU ku, vu;
        ku.u = kvs[2 * t];             // wave-uniform -> broadcast, no conflicts
        vu.u = kvs[2 * t + 1];

        float dA = dot2acc(qa[0].h[0], ku.h[0], 0.f);
        dA = dot2acc(qa[0].h[1], ku.h[1], dA);
        dA = dot2acc(qa[1].h[0], ku.h[2], dA);
        dA = dot2acc(qa[1].h[1], ku.h[3], dA);
        float dB = dot2acc(qb[0].h[0], ku.h[0], 0.f);
        dB = dot2acc(qb[0].h[1], ku.h[1], dB);
        dB = dot2acc(qb[1].h[0], ku.h[2], dB);
        dB = dot2acc(qb[1].h[1], ku.h[3], dB);

        float wA = fast_exp2(dA);
        float wB = fast_exp2(dB);
        denA += wA;
        denB += wB;
#pragma unroll
        for (int j = 0; j < 8; ++j) {
            float fv = (float)vu.s[j];             // fuses into v_fma_mix_f32
            accA[j] = __builtin_fmaf(wA, fv, accA[j]);
            accB[j] = __builtin_fmaf(wB, fv, accB[j]);
        }
    }

    float4* A4 = (float4*)(ACC + ((size_t)tc * NROWS + rowA) * E_DIM);
    A4[0] = make_float4(accA[0], accA[1], accA[2], accA[3]);
    A4[1] = make_float4(accA[4], accA[5], accA[6], accA[7]);
    float4* B4 = (float4*)(ACC + ((size_t)tc * NROWS + rowB) * E_DIM);
    B4[0] = make_float4(accB[0], accB[1], accB[2], accB[3]);
    B4[1] = make_float4(accB[4], accB[5], accB[6], accB[7]);
    DEN[(size_t)tc * NROWS + rowA] = denA;
    DEN[(size_t)tc * NROWS + rowB] = denB;
}

// Kernel 3: reduce partials across t-chunks, normalize, output projection.
__global__ __launch_bounds__(256) void finalize_kernel(
    const float* __restrict__ ACC, const float* __restrict__ DEN,
    const float* __restrict__ Wc, const float* __restrict__ bc,
    float* __restrict__ out, int tsplit)
{
    int row = blockIdx.x * blockDim.x + threadIdx.x;
    float a[8] = {0,0,0,0,0,0,0,0};
    float den = 0.f;
    for (int tc = 0; tc < tsplit; ++tc) {
        const float4* A4 = (const float4*)(ACC + ((size_t)tc * NROWS + row) * E_DIM);
        float4 p0 = A4[0], p1 = A4[1];
        a[0] += p0.x; a[1] += p0.y; a[2] += p0.z; a[3] += p0.w;
        a[4] += p1.x; a[5] += p1.y; a[6] += p1.z; a[7] += p1.w;
        den += DEN[(size_t)tc * NROWS + row];
    }
    float inv = 1.0f / den;
#pragma unroll
    for (int j = 0; j < 8; ++j) a[j] *= inv;
    float r[8];
#pragma unroll
    for (int i = 0; i < 8; ++i) {
        float h = bc[i];
#pragma unroll
        for (int j = 0; j < 8; ++j) h += a[j] * Wc[i * 8 + j];
        r[i] = h;
    }
    float4* O4 = (float4*)(out + (size_t)row * E_DIM);
    O4[0] = make_float4(r[0], r[1], r[2], r[3]);
    O4[1] = make_float4(r[4], r[5], r[6], r[7]);
}

extern "C" void kernel_launch(void* const* d_in, const int* in_sizes, int n_in,
                              void* d_out, int out_size, void* d_ws, size_t ws_size,
                              hipStream_t stream) {
    const float* x     = (const float*)d_in[0];
    const float* Wq    = (const float*)d_in[1];
    const float* bq    = (const float*)d_in[2];
    const float* Wk    = (const float*)d_in[3];
    const float* bk    = (const float*)d_in[4];
    const float* Wv    = (const float*)d_in[5];
    const float* bv    = (const float*)d_in[6];
    const float* theta = (const float*)d_in[7];
    const float* Wc    = (const float*)d_in[8];
    const float* bc    = (const float*)d_in[9];
    float* out = (float*)d_out;

    // ws layout (fp32 units): Qh = NROWS*2 u64 -> 4 f32/row; KVh = 8 f32/row;
    // ACC = tsplit*NROWS*8; DEN = tsplit*NROWS.
    const size_t qh_f = (size_t)NROWS * 4;
    const size_t kv_f = (size_t)NROWS * 8;
    auto need = [&](int ts) {
        return (qh_f + kv_f + (size_t)ts * NROWS * 9) * sizeof(float);
    };
    int tsplit = (ws_size >= need(32)) ? 32 : 16;   // 16 known to fit (R2 ran 20.4+ MB)

    float* ws  = (float*)d_ws;
    uint2* Qh  = (uint2*)ws;
    uint4* KVh = (uint4*)(ws + qh_f);
    float* ACC = ws + qh_f + kv_f;
    float* DEN = ACC + (size_t)tsplit * NROWS * E_DIM;

    qkv_kernel<<<NROWS / 256, 256, 0, stream>>>(x, Wq, bq, Wk, bk, Wv, bv, theta, Qh, KVh);

    dim3 grid2(NROWS / ROWS_PER_BLOCK, tsplit);     // (64, tsplit)
    if (tsplit == 32)
        attn_partial<32><<<grid2, 256, 0, stream>>>(Qh, KVh, ACC, DEN);
    else
        attn_partial<16><<<grid2, 256, 0, stream>>>(Qh, KVh, ACC, DEN);

    finalize_kernel<<<NROWS / 256, 256, 0, stream>>>(ACC, DEN, Wc, bc, out, tsplit);
}

// Round 4
// 153.041 us; speedup vs baseline: 1.0764x; 1.0305x over previous
//
#include <hip/hip_runtime.h>
#include <math.h>

#define E_DIM 8
#define S_DIM 4096
#define B_DIM 8
#define NROWS (B_DIM * S_DIM)          // 32768
#define ROWS_PER_BLOCK 1024            // 256 threads x 4 rows/lane

// 0.5 (attention scale 1/sqrt(E/NH)=0.5) * log2(e), folded into Q (before f16
// rounding) so the inner loop uses raw exp2.
#define QSCALE 0.72134752044448170f

typedef _Float16 h2 __attribute__((ext_vector_type(2)));

union HU {
    uint4 u;
    h2 h[4];
    _Float16 s[8];
};

__device__ inline float fast_exp2(float x) {
#if __has_builtin(__builtin_amdgcn_exp2f)
    return __builtin_amdgcn_exp2f(x);
#else
    return exp2f(x);
#endif
}

__device__ inline float dot2acc(h2 a, h2 b, float c) {
#if __has_builtin(__builtin_amdgcn_fdot2)
    return __builtin_amdgcn_fdot2(a, b, c, false);
#else
    return __builtin_fmaf((float)a.x, (float)b.x,
           __builtin_fmaf((float)a.y, (float)b.y, c));
#endif
}

// Kernel 1: Qh[row] = f16(cos(x@Wq.T+bq+theta)*QSCALE)  (16 B/row);
// KVh[row] = f16{k0..k7, v0..v7}  (32 B/row).
__global__ __launch_bounds__(256) void qkv_kernel(
    const float* __restrict__ x,
    const float* __restrict__ Wq, const float* __restrict__ bq,
    const float* __restrict__ Wk, const float* __restrict__ bk,
    const float* __restrict__ Wv, const float* __restrict__ bv,
    const float* __restrict__ theta,
    uint2* __restrict__ Qh, uint4* __restrict__ KVh)
{
    int row = blockIdx.x * blockDim.x + threadIdx.x;
    const float4* x4 = (const float4*)(x + (size_t)row * E_DIM);
    float4 xa = x4[0], xb = x4[1];
    float xr[8] = {xa.x, xa.y, xa.z, xa.w, xb.x, xb.y, xb.z, xb.w};

    float q[8], k[8], v[8];
#pragma unroll
    for (int i = 0; i < 8; ++i) {
        float hq = bq[i], hk = bk[i], hv = bv[i];
#pragma unroll
        for (int j = 0; j < 8; ++j) {
            hq += xr[j] * Wq[i * 8 + j];
            hk += xr[j] * Wk[i * 8 + j];
            hv += xr[j] * Wv[i * 8 + j];
        }
        float th = theta[i];
        q[i] = __cosf(hq + th) * QSCALE;
        k[i] = __cosf(hk + th);
        v[i] = __cosf(hv + th);
    }

    union { uint2 u; _Float16 s[4]; } qp[2];
#pragma unroll
    for (int i = 0; i < 8; ++i) qp[i / 4].s[i % 4] = (_Float16)q[i];
    Qh[(size_t)row * 2 + 0] = qp[0].u;
    Qh[(size_t)row * 2 + 1] = qp[1].u;

    HU kv0, kv1;
#pragma unroll
    for (int i = 0; i < 8; ++i) { kv0.s[i] = (_Float16)k[i]; kv1.s[i] = (_Float16)v[i]; }
    KVh[(size_t)row * 2 + 0] = kv0.u;
    KVh[(size_t)row * 2 + 1] = kv1.u;
}

// Kernel 2: flash-style partial over one t-chunk; 4 rows per lane so each
// pair of ds_read_b128 broadcasts feeds 256 (row,t) pairs of work.
// No max-subtraction needed (|score*log2e| <= 5.8, exp2 bounded ~54.6).
template <int TSPLIT>
__global__ __launch_bounds__(256) void attn_partial(
    const uint2* __restrict__ Qh, const uint4* __restrict__ KVh,
    float* __restrict__ ACC, float* __restrict__ DEN)
{
    constexpr int TCH = S_DIM / TSPLIT;
    __shared__ uint4 kvs[TCH * 2];     // 32 B per t

    int rb = blockIdx.x;               // row-block: 0..31
    int tc = blockIdx.y;               // t-chunk
    int tid = threadIdx.x;
    int batch = rb >> 2;               // 4 row-blocks of 1024 per batch

    // stage chunk: TCH*2 uint4 (256 at TSPLIT=32 -> 1 per thread)
    const uint4* src = KVh + ((size_t)batch * S_DIM + (size_t)tc * TCH) * 2;
    for (int i = tid; i < TCH * 2; i += 256) kvs[i] = src[i];

    int row0 = rb * ROWS_PER_BLOCK + tid;
    union { uint2 u; h2 h[2]; } q[4][2];
#pragma unroll
    for (int r = 0; r < 4; ++r) {
        q[r][0].u = Qh[(size_t)(row0 + r * 256) * 2 + 0];
        q[r][1].u = Qh[(size_t)(row0 + r * 256) * 2 + 1];
    }
    __syncthreads();

    float acc[4][8];
#pragma unroll
    for (int r = 0; r < 4; ++r)
#pragma unroll
        for (int j = 0; j < 8; ++j) acc[r][j] = 0.f;
    float den[4] = {0.f, 0.f, 0.f, 0.f};

#pragma unroll 4
    for (int t = 0; t < TCH; ++t) {
        HU ku, vu;
        ku.u = kvs[2 * t];             // wave-uniform -> broadcast, no conflicts
        vu.u = kvs[2 * t + 1];

        float w[4];
#pragma unroll
        for (int r = 0; r < 4; ++r) {
            float d = dot2acc(q[r][0].h[0], ku.h[0], 0.f);
            d = dot2acc(q[r][0].h[1], ku.h[1], d);
            d = dot2acc(q[r][1].h[0], ku.h[2], d);
            d = dot2acc(q[r][1].h[1], ku.h[3], d);
            w[r] = fast_exp2(d);
            den[r] += w[r];
        }
#pragma unroll
        for (int r = 0; r < 4; ++r)
#pragma unroll
            for (int j = 0; j < 8; ++j) {
                float fv = (float)vu.s[j];         // fuses into v_fma_mix_f32
                acc[r][j] = __builtin_fmaf(w[r], fv, acc[r][j]);
            }
    }

#pragma unroll
    for (int r = 0; r < 4; ++r) {
        int row = row0 + r * 256;
        float4* A4 = (float4*)(ACC + ((size_t)tc * NROWS + row) * E_DIM);
        A4[0] = make_float4(acc[r][0], acc[r][1], acc[r][2], acc[r][3]);
        A4[1] = make_float4(acc[r][4], acc[r][5], acc[r][6], acc[r][7]);
        DEN[(size_t)tc * NROWS + row] = den[r];
    }
}

// Kernel 3: reduce partials across t-chunks, normalize, output projection.
__global__ __launch_bounds__(256) void finalize_kernel(
    const float* __restrict__ ACC, const float* __restrict__ DEN,
    const float* __restrict__ Wc, const float* __restrict__ bc,
    float* __restrict__ out, int tsplit)
{
    int row = blockIdx.x * blockDim.x + threadIdx.x;
    float a[8] = {0,0,0,0,0,0,0,0};
    float den = 0.f;
    for (int tc = 0; tc < tsplit; ++tc) {
        const float4* A4 = (const float4*)(ACC + ((size_t)tc * NROWS + row) * E_DIM);
        float4 p0 = A4[0], p1 = A4[1];
        a[0] += p0.x; a[1] += p0.y; a[2] += p0.z; a[3] += p0.w;
        a[4] += p1.x; a[5] += p1.y; a[6] += p1.z; a[7] += p1.w;
        den += DEN[(size_t)tc * NROWS + row];
    }
    float inv = 1.0f / den;
#pragma unroll
    for (int j = 0; j < 8; ++j) a[j] *= inv;
    float r[8];
#pragma unroll
    for (int i = 0; i < 8; ++i) {
        float h = bc[i];
#pragma unroll
        for (int j = 0; j < 8; ++j) h += a[j] * Wc[i * 8 + j];
        r[i] = h;
    }
    float4* O4 = (float4*)(out + (size_t)row * E_DIM);
    O4[0] = make_float4(r[0], r[1], r[2], r[3]);
    O4[1] = make_float4(r[4], r[5], r[6], r[7]);
}

extern "C" void kernel_launch(void* const* d_in, const int* in_sizes, int n_in,
                              void* d_out, int out_size, void* d_ws, size_t ws_size,
                              hipStream_t stream) {
    const float* x     = (const float*)d_in[0];
    const float* Wq    = (const float*)d_in[1];
    const float* bq    = (const float*)d_in[2];
    const float* Wk    = (const float*)d_in[3];
    const float* bk    = (const float*)d_in[4];
    const float* Wv    = (const float*)d_in[5];
    const float* bv    = (const float*)d_in[6];
    const float* theta = (const float*)d_in[7];
    const float* Wc    = (const float*)d_in[8];
    const float* bc    = (const float*)d_in[9];
    float* out = (float*)d_out;

    // ws layout (f32 units): Qh 4/row, KVh 8/row, ACC tsplit*8/row, DEN tsplit/row
    const size_t qh_f = (size_t)NROWS * 4;
    const size_t kv_f = (size_t)NROWS * 8;
    auto need = [&](int ts) {
        return (qh_f + kv_f + (size_t)ts * NROWS * 9) * sizeof(float);
    };
    int tsplit = (ws_size >= need(32)) ? 32 : 16;   // 32 fit in R3

    float* ws  = (float*)d_ws;
    uint2* Qh  = (uint2*)ws;
    uint4* KVh = (uint4*)(ws + qh_f);
    float* ACC = ws + qh_f + kv_f;
    float* DEN = ACC + (size_t)tsplit * NROWS * E_DIM;

    qkv_kernel<<<NROWS / 256, 256, 0, stream>>>(x, Wq, bq, Wk, bk, Wv, bv, theta, Qh, KVh);

    dim3 grid2(NROWS / ROWS_PER_BLOCK, tsplit);     // (32, tsplit)
    if (tsplit == 32)
        attn_partial<32><<<grid2, 256, 0, stream>>>(Qh, KVh, ACC, DEN);
    else
        attn_partial<16><<<grid2, 256, 0, stream>>>(Qh, KVh, ACC, DEN);

    finalize_kernel<<<NROWS / 256, 256, 0, stream>>>(ACC, DEN, Wc, bc, out, tsplit);
}

// Round 6
// 102.572 us; speedup vs baseline: 1.6060x; 1.4920x over previous
//
#include <hip/hip_runtime.h>
#include <math.h>

#define E_DIM 8
#define S_DIM 4096
#define B_DIM 8
#define NROWS (B_DIM * S_DIM)          // 32768
#define TCH 512                        // t-chunk staged in LDS
#define NCHUNK (S_DIM / TCH)           // 8
#define VSTRIDE 516                    // V^T row stride (pad breaks 16-way bank conflict)

// 0.5 (attention scale 1/sqrt(E/NH)=0.5) * log2(e), folded into Q before f16
// rounding so scores come out of the QK mfma ready for raw exp2.
#define QSCALE 0.72134752044448170f

typedef __attribute__((ext_vector_type(4))) float f4;
typedef __attribute__((ext_vector_type(4))) __fp16 h4;
typedef __attribute__((ext_vector_type(2))) __fp16 h2t;

union HU { uint4 u; __fp16 s[8]; };
union QU { uint2 u; h4 h; };

__device__ inline float fast_exp2(float x) {
#if __has_builtin(__builtin_amdgcn_exp2f)
    return __builtin_amdgcn_exp2f(x);
#else
    return exp2f(x);
#endif
}

// Kernel 1: Qh[row] = f16(cos(x@Wq.T+bq+theta)*QSCALE) (16 B/row);
// KVh[row] = f16{k0..k7, v0..v7} (32 B/row).
__global__ __launch_bounds__(256) void qkv_kernel(
    const float* __restrict__ x,
    const float* __restrict__ Wq, const float* __restrict__ bq,
    const float* __restrict__ Wk, const float* __restrict__ bk,
    const float* __restrict__ Wv, const float* __restrict__ bv,
    const float* __restrict__ theta,
    uint2* __restrict__ Qh, uint4* __restrict__ KVh)
{
    int row = blockIdx.x * blockDim.x + threadIdx.x;
    const float4* x4 = (const float4*)(x + (size_t)row * E_DIM);
    float4 xa = x4[0], xb = x4[1];
    float xr[8] = {xa.x, xa.y, xa.z, xa.w, xb.x, xb.y, xb.z, xb.w};

    float q[8], k[8], v[8];
#pragma unroll
    for (int i = 0; i < 8; ++i) {
        float hq = bq[i], hk = bk[i], hv = bv[i];
#pragma unroll
        for (int j = 0; j < 8; ++j) {
            hq += xr[j] * Wq[i * 8 + j];
            hk += xr[j] * Wk[i * 8 + j];
            hv += xr[j] * Wv[i * 8 + j];
        }
        float th = theta[i];
        q[i] = __cosf(hq + th) * QSCALE;
        k[i] = __cosf(hk + th);
        v[i] = __cosf(hv + th);
    }

    union { uint2 u; __fp16 s[4]; } qp[2];
#pragma unroll
    for (int i = 0; i < 8; ++i) qp[i / 4].s[i % 4] = (__fp16)q[i];
    Qh[(size_t)row * 2 + 0] = qp[0].u;
    Qh[(size_t)row * 2 + 1] = qp[1].u;

    HU kv0, kv1;
#pragma unroll
    for (int i = 0; i < 8; ++i) { kv0.s[i] = (__fp16)k[i]; kv1.s[i] = (__fp16)v[i]; }
    KVh[(size_t)row * 2 + 0] = kv0.u;
    KVh[(size_t)row * 2 + 1] = kv1.u;
}

// Kernel 2: full-MFMA flash attention. Each wave owns 16 rows of one batch
// and sweeps all 4096 t in LDS-staged chunks of 512.
//  - S^T tile = mfma(A=K_frag(e zero-padded to 16), B=Q_frag)
//  - P = exp2(S^T) lands lane-local in exactly the A-layout the PV mfma needs
//  - C += mfma(A=P, B=V^T_frag); V^T row e=8 is all-ones -> C col 8 = denom
// Epilogue: shfl denom, normalize, LDS transpose, fused Wc projection.
// grid = 512 blocks x 256 thr (4 waves = 64 rows/block; 64 blocks/batch).
__global__ __launch_bounds__(256) void attn_mfma(
    const uint2* __restrict__ Qh, const uint4* __restrict__ KVh,
    const float* __restrict__ Wc, const float* __restrict__ bc,
    float* __restrict__ out)
{
    __shared__ __align__(16) __fp16 Kpad[TCH * 16];     // 16 KB, rows padded e=8..15 zero
    __shared__ __align__(16) __fp16 Vt[16 * VSTRIDE];   // 16.1 KB, V transposed

    int tid = threadIdx.x;
    int l = tid & 63;
    int wv = tid >> 6;
    int b = blockIdx.x;
    int batch = b >> 6;
    int rbase = b * 64 + wv * 16;      // wave's 16 global rows

    // one-time constant LDS init (never overwritten by staging):
    // K rows' upper 16 B (e=8..15) = 0
    for (int r = tid; r < TCH; r += 256)
        *((uint4*)(Kpad + r * 16 + 8)) = make_uint4(0, 0, 0, 0);
    // Vt rows 9..15 = 0
    {
        uint* z = (uint*)(Vt + 9 * VSTRIDE);
        for (int i = tid; i < 7 * VSTRIDE / 2; i += 256) z[i] = 0;
    }
    // Vt row 8 = 1.0 (denominator column)
    for (int i = tid; i < VSTRIDE; i += 256) Vt[8 * VSTRIDE + i] = (__fp16)1.0f;

    // Q fragment (loop-invariant): B[k=e][n=r], lane l reg i = Q[r=l&15][e=4*(l>>4)+i]
    QU qu; qu.u = make_uint2(0, 0);
    if ((l >> 4) < 2)
        qu.u = Qh[(size_t)(rbase + (l & 15)) * 2 + (l >> 4)];
    h4 qf = qu.h;

    f4 C = {0.f, 0.f, 0.f, 0.f};

    for (int ch = 0; ch < NCHUNK; ++ch) {
        __syncthreads();   // covers init on ch=0, prev-chunk compute after
        const uint4* src = KVh + ((size_t)batch * S_DIM + (size_t)ch * TCH) * 2;
        for (int tl = tid; tl < TCH; tl += 256) {
            uint4 kk = src[tl * 2];
            uint4 vvu = src[tl * 2 + 1];
            *((uint4*)(Kpad + tl * 16)) = kk;   // lower 16 B; upper stays zero
            HU vv; vv.u = vvu;
#pragma unroll
            for (int e = 0; e < 8; ++e)
                Vt[e * VSTRIDE + tl] = vv.s[e];  // 2B-stride writes: 2-way = free
        }
        __syncthreads();

#pragma unroll 4
        for (int s = 0; s < TCH / 16; ++s) {
            int ts = s * 16;
            // A=K: lane l reg i = K[ts + (l&15)][e=4*(l>>4)+i] (zeros for e>=8)
            h4 kf = *((const h4*)(Kpad + ((ts + (l & 15)) << 4) + ((l >> 4) << 2)));
            f4 sc = __builtin_amdgcn_mfma_f32_16x16x16f16(
                kf, qf, (f4){0.f, 0.f, 0.f, 0.f}, 0, 0, 0);   // S^T tile
            float e0 = fast_exp2(sc[0]);
            float e1 = fast_exp2(sc[1]);
            float e2 = fast_exp2(sc[2]);
            float e3 = fast_exp2(sc[3]);
            h2t p0 = __builtin_amdgcn_cvt_pkrtz(e0, e1);
            h2t p1 = __builtin_amdgcn_cvt_pkrtz(e2, e3);
            h4 af = __builtin_shufflevector(p0, p1, 0, 1, 2, 3);
            // B=V^T: lane l reg i = V[ts+4*(l>>4)+i][e=l&15] (row8=1, rows9-15=0)
            h4 vf = *((const h4*)(Vt + (l & 15) * VSTRIDE + ts + ((l >> 4) << 2)));
            C = __builtin_amdgcn_mfma_f32_16x16x16f16(af, vf, C, 0, 0, 0);
        }
    }
    __syncthreads();   // done with Kpad/Vt as staged data

    // C: lane l reg i = O[row r=4*(l>>4)+i][col e=l&15]; col 8 = denom.
    float o[4];
#pragma unroll
    for (int i = 0; i < 4; ++i) {
        float d = __shfl(C[i], (l & 48) | 8, 64);
        o[i] = C[i] / d;
    }

    // LDS transpose patch (reuse Kpad): 16 rows x 8 e (stride 9 f32) per wave
    float* patch = ((float*)Kpad) + wv * 160;
    if ((l & 15) < 8) {
#pragma unroll
        for (int i = 0; i < 4; ++i)
            patch[(((l >> 4) << 2) + i) * 9 + (l & 15)] = o[i];
    }
    __syncthreads();

    // fused output projection: lane l handles row r2=l>>2, cols ep, ep+1
    int r2 = l >> 2;
    int ep = (l & 3) * 2;
    float vrow[8];
#pragma unroll
    for (int j = 0; j < 8; ++j) vrow[j] = patch[r2 * 9 + j];
    float o0 = bc[ep], o1 = bc[ep + 1];
#pragma unroll
    for (int j = 0; j < 8; ++j) {
        o0 = __builtin_fmaf(vrow[j], Wc[ep * 8 + j], o0);
        o1 = __builtin_fmaf(vrow[j], Wc[(ep + 1) * 8 + j], o1);
    }
    *((float2*)(out + (size_t)(rbase + r2) * 8 + ep)) = make_float2(o0, o1);
}

extern "C" void kernel_launch(void* const* d_in, const int* in_sizes, int n_in,
                              void* d_out, int out_size, void* d_ws, size_t ws_size,
                              hipStream_t stream) {
    const float* x     = (const float*)d_in[0];
    const float* Wq    = (const float*)d_in[1];
    const float* bq    = (const float*)d_in[2];
    const float* Wk    = (const float*)d_in[3];
    const float* bk    = (const float*)d_in[4];
    const float* Wv    = (const float*)d_in[5];
    const float* bv    = (const float*)d_in[6];
    const float* theta = (const float*)d_in[7];
    const float* Wc    = (const float*)d_in[8];
    const float* bc    = (const float*)d_in[9];
    float* out = (float*)d_out;

    // ws: Qh (16 B/row) + KVh (32 B/row) = 1.5 MB total. No ACC/DEN anymore.
    float* ws  = (float*)d_ws;
    uint2* Qh  = (uint2*)ws;
    uint4* KVh = (uint4*)(ws + (size_t)NROWS * 4);

    qkv_kernel<<<NROWS / 256, 256, 0, stream>>>(x, Wq, bq, Wk, bk, Wv, bv, theta, Qh, KVh);

    attn_mfma<<<NROWS / 64, 256, 0, stream>>>(Qh, KVh, Wc, bc, out);
}

// Round 7
// 100.828 us; speedup vs baseline: 1.6338x; 1.0173x over previous
//
#include <hip/hip_runtime.h>
#include <math.h>

#define E_DIM 8
#define S_DIM 4096
#define B_DIM 8
#define NROWS (B_DIM * S_DIM)          // 32768
#define TCH 512                        // t-chunk staged in LDS
#define TSPLIT 4                       // t-splits (chunks per block = 1024/TCH = 2)
#define VSTRIDE 520                    // V^T LDS row stride in halves (16B-aligned, banks spread)

// 0.5 (attention scale 1/sqrt(E/NH)=0.5) * log2(e), folded into Q before f16
// rounding so scores come out of the QK mfma ready for raw exp2.
#define QSCALE 0.72134752044448170f

typedef __attribute__((ext_vector_type(4))) float f4;
typedef __attribute__((ext_vector_type(4))) __fp16 h4;
typedef __attribute__((ext_vector_type(8))) __fp16 h8;

union QU { uint2 u; h4 h; };

__device__ inline float fast_exp2(float x) {
#if __has_builtin(__builtin_amdgcn_exp2f)
    return __builtin_amdgcn_exp2f(x);
#else
    return exp2f(x);
#endif
}

// Kernel 1: Qh[row] = f16(cos(x@Wq.T+bq+theta)*QSCALE)  (16 B/row);
// Kg[row]  = f16 k[0..7]                                 (16 B/row);
// VTg[batch][e][t] = f16 v  (global V-transpose so attn staging is vector copies).
__global__ __launch_bounds__(256) void qkv_kernel(
    const float* __restrict__ x,
    const float* __restrict__ Wq, const float* __restrict__ bq,
    const float* __restrict__ Wk, const float* __restrict__ bk,
    const float* __restrict__ Wv, const float* __restrict__ bv,
    const float* __restrict__ theta,
    uint4* __restrict__ Qh, uint4* __restrict__ Kg, __fp16* __restrict__ VTg)
{
    int row = blockIdx.x * blockDim.x + threadIdx.x;
    const float4* x4 = (const float4*)(x + (size_t)row * E_DIM);
    float4 xa = x4[0], xb = x4[1];
    float xr[8] = {xa.x, xa.y, xa.z, xa.w, xb.x, xb.y, xb.z, xb.w};

    float q[8], k[8], v[8];
#pragma unroll
    for (int i = 0; i < 8; ++i) {
        float hq = bq[i], hk = bk[i], hv = bv[i];
#pragma unroll
        for (int j = 0; j < 8; ++j) {
            hq += xr[j] * Wq[i * 8 + j];
            hk += xr[j] * Wk[i * 8 + j];
            hv += xr[j] * Wv[i * 8 + j];
        }
        float th = theta[i];
        q[i] = __cosf(hq + th) * QSCALE;
        k[i] = __cosf(hk + th);
        v[i] = __cosf(hv + th);
    }

    union { uint4 u; __fp16 s[8]; } qp, kp;
#pragma unroll
    for (int i = 0; i < 8; ++i) { qp.s[i] = (__fp16)q[i]; kp.s[i] = (__fp16)k[i]; }
    Qh[row] = qp.u;
    Kg[row] = kp.u;

    int batch = row >> 12;
    int t = row & 4095;
#pragma unroll
    for (int e = 0; e < 8; ++e)     // coalesced across lanes (t contiguous)
        VTg[((size_t)(batch * 8 + e) << 12) + t] = (__fp16)v[e];
}

// Kernel 2: full-MFMA flash attention, 32 rows/wave (2 Q-tiles share every
// K/V fragment read), t-split partials (no rescale needed: scores bounded).
// t processed in permuted order t = ch_base + 32*ds + 8*g + 4*s' + i so one
// ds_read_b128 of V^T feeds two mfma steps (lo/hi). V^T LDS row 8 = ones ->
// accumulator col 8 = denominator.
// grid = (NROWS/128, TSPLIT), block = 256 (4 waves x 32 rows).
__global__ __launch_bounds__(256) void attn_mfma(
    const uint4* __restrict__ Qh, const uint4* __restrict__ Kg,
    const __fp16* __restrict__ VTg,
    float* __restrict__ ACC, float* __restrict__ DEN)
{
    __shared__ __align__(16) __fp16 Kpad[TCH * 16];      // 16 KB; e=8..15 zero
    __shared__ __align__(16) __fp16 Vt[16 * VSTRIDE];    // 16.25 KB; row8=1, rows9-15=0

    int tid = threadIdx.x;
    int l = tid & 63;
    int wv = tid >> 6;
    int rb = blockIdx.x;               // 0..255 row-groups of 128
    int sp = blockIdx.y;               // t-split 0..3
    int batch = rb >> 5;
    int rbase = rb * 128 + wv * 32;    // wave's 32 global rows

    // one-time constant LDS init (never overwritten by staging):
    for (int r = tid; r < TCH; r += 256)                       // K rows e=8..15 = 0
        *((uint4*)(Kpad + r * 16 + 8)) = make_uint4(0, 0, 0, 0);
    {
        uint* z = (uint*)(Vt + 9 * VSTRIDE);                   // Vt rows 9..15 = 0
        for (int i = tid; i < 7 * VSTRIDE / 2; i += 256) z[i] = 0;
        uint* o1 = (uint*)(Vt + 8 * VSTRIDE);                  // Vt row 8 = 1.0
        for (int i = tid; i < VSTRIDE / 2; i += 256) o1[i] = 0x3C003C00u;
    }

    // Q fragments (loop-invariant): B[k=e][n=r]; lanes 32..63 give e>=8 -> 0
    QU q0u, q1u; q0u.u = make_uint2(0, 0); q1u.u = make_uint2(0, 0);
    if ((l >> 4) < 2) {
        const uint2* Q2 = (const uint2*)Qh;
        q0u.u = Q2[(size_t)(rbase + (l & 15)) * 2 + (l >> 4)];
        q1u.u = Q2[(size_t)(rbase + 16 + (l & 15)) * 2 + (l >> 4)];
    }
    h4 qf0 = q0u.h, qf1 = q1u.h;

    // per-lane fragment address constants
    int koff = ((l & 12) << 1) + (l & 3);            // 8*((l&15)>>2) + (l&3)
    int voff = (l & 15) * VSTRIDE + ((l >> 4) << 3); // halves

    f4 C0 = {0.f, 0.f, 0.f, 0.f};
    f4 C1 = {0.f, 0.f, 0.f, 0.f};

    for (int ch = 0; ch < 1024 / TCH; ++ch) {
        int tb = sp * 1024 + ch * TCH;               // chunk base t within batch
        __syncthreads();                             // covers init / prev compute
        // stage K: 512 rows x 16 B
        {
            const uint4* src = Kg + ((size_t)batch << 12) + tb;
            for (int i = tid; i < TCH; i += 256)
                *((uint4*)(Kpad + i * 16)) = src[i];
        }
        // stage V^T: 8 rows x 512 halves (vector copies, no scatter)
        {
            for (int i = tid; i < 8 * (TCH / 8); i += 256) {   // 512 uint4
                int e = i >> 6, c = i & 63;
                const uint4* src = (const uint4*)(VTg + (((size_t)(batch * 8 + e)) << 12) + tb);
                *((uint4*)(Vt + e * VSTRIDE + c * 8)) = src[c];
            }
        }
        __syncthreads();

#pragma unroll 4
        for (int ds = 0; ds < TCH / 32; ++ds) {      // 16 double-steps of 32 t
            int krow = ds * 32 + koff;
            h4 kf0 = *((const h4*)(Kpad + (krow << 4) + ((l >> 4) << 2)));
            h4 kf1 = *((const h4*)(Kpad + ((krow + 4) << 4) + ((l >> 4) << 2)));
            h8 vr = *((const h8*)(Vt + voff + ds * 32));
            h4 vlo = __builtin_shufflevector(vr, vr, 0, 1, 2, 3);
            h4 vhi = __builtin_shufflevector(vr, vr, 4, 5, 6, 7);

            f4 z = {0.f, 0.f, 0.f, 0.f};
            f4 s00 = __builtin_amdgcn_mfma_f32_16x16x16f16(kf0, qf0, z, 0, 0, 0);
            f4 s01 = __builtin_amdgcn_mfma_f32_16x16x16f16(kf1, qf0, z, 0, 0, 0);
            f4 s10 = __builtin_amdgcn_mfma_f32_16x16x16f16(kf0, qf1, z, 0, 0, 0);
            f4 s11 = __builtin_amdgcn_mfma_f32_16x16x16f16(kf1, qf1, z, 0, 0, 0);

            h4 p00, p01, p10, p11;
#pragma unroll
            for (int i = 0; i < 4; ++i) {
                p00[i] = (__fp16)fast_exp2(s00[i]);
                p01[i] = (__fp16)fast_exp2(s01[i]);
                p10[i] = (__fp16)fast_exp2(s10[i]);
                p11[i] = (__fp16)fast_exp2(s11[i]);
            }
            C0 = __builtin_amdgcn_mfma_f32_16x16x16f16(p00, vlo, C0, 0, 0, 0);
            C0 = __builtin_amdgcn_mfma_f32_16x16x16f16(p01, vhi, C0, 0, 0, 0);
            C1 = __builtin_amdgcn_mfma_f32_16x16x16f16(p10, vlo, C1, 0, 0, 0);
            C1 = __builtin_amdgcn_mfma_f32_16x16x16f16(p11, vhi, C1, 0, 0, 0);
        }
    }

    // C: lane l reg i = Onum[row 4*(l>>4)+i][e=l&15]; col 8 = denominator.
    int e = l & 15;
    int g = l >> 4;
#pragma unroll
    for (int i = 0; i < 4; ++i) {
        int r0 = rbase + 4 * g + i;
        if (e < 8) {
            ACC[(((size_t)sp * NROWS + r0) << 3) + e] = C0[i];
            ACC[(((size_t)sp * NROWS + r0 + 16) << 3) + e] = C1[i];
        } else if (e == 8) {
            DEN[(size_t)sp * NROWS + r0] = C0[i];
            DEN[(size_t)sp * NROWS + r0 + 16] = C1[i];
        }
    }
}

// Kernel 3: combine t-split partials, normalize, fused Wc projection.
__global__ __launch_bounds__(256) void finalize_kernel(
    const float* __restrict__ ACC, const float* __restrict__ DEN,
    const float* __restrict__ Wc, const float* __restrict__ bc,
    float* __restrict__ out)
{
    int row = blockIdx.x * blockDim.x + threadIdx.x;
    float a[8] = {0,0,0,0,0,0,0,0};
    float den = 0.f;
#pragma unroll
    for (int sp = 0; sp < TSPLIT; ++sp) {
        const float4* A4 = (const float4*)(ACC + (((size_t)sp * NROWS + row) << 3));
        float4 p0 = A4[0], p1 = A4[1];
        a[0] += p0.x; a[1] += p0.y; a[2] += p0.z; a[3] += p0.w;
        a[4] += p1.x; a[5] += p1.y; a[6] += p1.z; a[7] += p1.w;
        den += DEN[(size_t)sp * NROWS + row];
    }
    float inv = 1.0f / den;
#pragma unroll
    for (int j = 0; j < 8; ++j) a[j] *= inv;
    float r[8];
#pragma unroll
    for (int i = 0; i < 8; ++i) {
        float h = bc[i];
#pragma unroll
        for (int j = 0; j < 8; ++j) h += a[j] * Wc[i * 8 + j];
        r[i] = h;
    }
    float4* O4 = (float4*)(out + (size_t)row * 8);
    O4[0] = make_float4(r[0], r[1], r[2], r[3]);
    O4[1] = make_float4(r[4], r[5], r[6], r[7]);
}

extern "C" void kernel_launch(void* const* d_in, const int* in_sizes, int n_in,
                              void* d_out, int out_size, void* d_ws, size_t ws_size,
                              hipStream_t stream) {
    const float* x     = (const float*)d_in[0];
    const float* Wq    = (const float*)d_in[1];
    const float* bq    = (const float*)d_in[2];
    const float* Wk    = (const float*)d_in[3];
    const float* bk    = (const float*)d_in[4];
    const float* Wv    = (const float*)d_in[5];
    const float* bv    = (const float*)d_in[6];
    const float* theta = (const float*)d_in[7];
    const float* Wc    = (const float*)d_in[8];
    const float* bc    = (const float*)d_in[9];
    float* out = (float*)d_out;

    // ws (f32 units): Qh 4/row, Kg 4/row, VTg 4/row, ACC TSPLIT*8/row, DEN TSPLIT/row
    float* ws  = (float*)d_ws;
    uint4*  Qh  = (uint4*)ws;
    uint4*  Kg  = (uint4*)(ws + (size_t)NROWS * 4);
    __fp16* VTg = (__fp16*)(ws + (size_t)NROWS * 8);
    float*  ACC = ws + (size_t)NROWS * 12;
    float*  DEN = ACC + (size_t)TSPLIT * NROWS * 8;
    // total = 32768*(12 + 32 + 4) * 4 B = 6.3 MB

    qkv_kernel<<<NROWS / 256, 256, 0, stream>>>(x, Wq, bq, Wk, bk, Wv, bv, theta, Qh, Kg, VTg);

    dim3 grid2(NROWS / 128, TSPLIT);   // (256, 4)
    attn_mfma<<<grid2, 256, 0, stream>>>(Qh, Kg, VTg, ACC, DEN);

    finalize_kernel<<<NROWS / 256, 256, 0, stream>>>(ACC, DEN, Wc, bc, out);
}